// Round 12
// baseline (317.781 us; speedup 1.0000x reference)
//
#include <hip/hip_runtime.h>
#include <math.h>

#define B_N   2048
#define NM    128
#define M_N   256
#define LNUM  10
#define EPS_Sf 1e-6f

typedef _Float16 half8 __attribute__((ext_vector_type(8)));
typedef float floatx4 __attribute__((ext_vector_type(4)));

__device__ __forceinline__ float frcp(float x) { return __builtin_amdgcn_rcpf(x); }

// ---------------- workspace layout (float offsets) ----------------
static constexpr size_t o_AA  = 0;                       // 2 f16 planes, frag order
static constexpr size_t o_D   = o_AA  + 131072;          // 256
static constexpr size_t o_yn  = o_D   + 256;             // 2048
static constexpr size_t o_AY  = o_yn  + 2048;            // (unused)
static constexpr size_t o_AYt = o_AY  + 1048576;         // [2][256][2048]
static constexpr size_t o_w2t = o_AYt + 1048576;         // Wa f16 [oc64][kk9][ic32]
static constexpr size_t o_z1  = o_w2t + 18432;           // (unused — conv1 fused into conv2)
static constexpr size_t o_fp  = o_z1  + 16777216;        // [16][64][2048] fp32 partials
static constexpr size_t o_f   = o_fp  + 2097152;         // [64][2048]
static constexpr size_t o_c   = o_f   + 131072;          // [2048][9]
static constexpr size_t o_dd  = o_c   + 18432;           // [2048][9]
static constexpr size_t o_T   = o_dd  + 18432;           // [2048][10]
static constexpr size_t o_Ua  = o_T   + 20480;           // 524288
static constexpr size_t o_gm  = o_Ua  + 524288;          // 1

// ---------------- K_pre: fused {gm=0, AA->f16 frag, w2t, AYt} ----------------
__global__ void k_pre(const float* __restrict__ Ar, const float* __restrict__ Ai,
                      const float* __restrict__ Yr, const float* __restrict__ Yi,
                      const float* __restrict__ w2, float* __restrict__ ws) {
    __shared__ float sb[2048];
    int blk = blockIdx.x;
    int tid = threadIdx.x;
    if (blk < 256) {
        float* cr = sb; float* ci = sb + NM;
        int i = blk, j = tid;
        if (j < NM) { cr[j] = Ar[j * M_N + i]; ci[j] = Ai[j * M_N + i]; }
        __syncthreads();
        float sr = 0.f, si = 0.f;
        for (int n = 0; n < NM; ++n) {
            float ar = Ar[n * M_N + j], ai = Ai[n * M_N + j];
            sr += cr[n] * ar + ci[n] * ai;
            si += cr[n] * ai - ci[n] * ar;
        }
        _Float16* A16 = (_Float16*)(ws + o_AA);
        size_t off = ((size_t)((i >> 4) * 8 + (j >> 5)) * 64
                      + (size_t)(((j >> 3) & 3) * 16 + (i & 15))) * 8 + (j & 7);
        A16[off]         = (_Float16)sr;
        A16[65536 + off] = (_Float16)si;
        if (j == i) ws[o_D + i] = sr;
        if (i == 0 && j == 0) *(unsigned int*)(ws + o_gm) = 0u;
    } else if (blk < 328) {
        int i = (blk - 256) * 256 + tid;
        if (i < 64 * 32 * 9) {
            int oc = i / 288, r = i % 288;
            int ic = r / 9, kk = r % 9;
            _Float16* Wa = (_Float16*)(ws + o_w2t);
            Wa[((size_t)oc * 9 + kk) * 32 + ic] = (_Float16)w2[i];
        }
    } else {
        float2* Ys = (float2*)sb;
        int bb0 = (blk - 328) * 8;
        for (int i = tid; i < 8 * NM; i += 256) {
            int g = i >> 7, n = i & 127;
            Ys[g * NM + n] = make_float2(Yr[(size_t)(bb0 + g) * NM + n],
                                         Yi[(size_t)(bb0 + g) * NM + n]);
        }
        __syncthreads();
        if (tid < 8) {
            float s = 0.f;
            for (int n = 0; n < NM; ++n) { float2 y = Ys[tid * NM + n]; s += y.x * y.x + y.y * y.y; }
            ws[o_yn + bb0 + tid] = s;
        }
        int m = tid;
        float accr[8], acci[8];
#pragma unroll
        for (int g = 0; g < 8; ++g) { accr[g] = 0.f; acci[g] = 0.f; }
        for (int n = 0; n < NM; ++n) {
            float ar = Ar[n * M_N + m], ai = Ai[n * M_N + m];
#pragma unroll
            for (int g = 0; g < 8; ++g) {
                float2 y = Ys[g * NM + n];
                accr[g] += ar * y.x + ai * y.y;
                acci[g] += ar * y.y - ai * y.x;
            }
        }
#pragma unroll
        for (int g = 0; g < 8; ++g) {
            ws[o_AYt + (size_t)m * B_N + (bb0 + g)] = accr[g];
            ws[o_AYt + 524288 + (size_t)m * B_N + (bb0 + g)] = acci[g];
        }
    }
}

// ---------------- K23: fused conv1+conv2 — z1 tile lives only in LDS ----------------
// grid 2048 = 128 b-tiles(16) x 16 m-groups(16). block 128 = 2 waves (32 oc each).
// Per block: stage AYt 20x20x2 window -> conv1 into zt[18][18][32] f16 (LDS, zero halo)
// -> implicit-GEMM MFMA with B-frags as dense 1KB LDS wave reads. No z1t in HBM.
#define MFMA16(A,Bv,C) C = __builtin_amdgcn_mfma_f32_16x16x32_f16(A, Bv, C, 0, 0, 0)
__global__ void __launch_bounds__(128)
k_conv12(const float* __restrict__ w1, const float* __restrict__ b1,
         const float* __restrict__ b2, float* __restrict__ ws) {
    __shared__ float xw[2][20][20];
    __shared__ float w1s[576], b1s[32];
    __shared__ __align__(16) _Float16 zt[18][18][32];     // 20.25 KB
    int tid = threadIdx.x;
    int lane = tid & 63, wv = tid >> 6;
    int col = lane & 15, quad = lane >> 4;
    int bt = blockIdx.x & 127, g = blockIdx.x >> 7;
    int b0 = bt * 16, m0 = g * 16;

    for (int i = tid; i < 576; i += 128) w1s[i] = w1[i];
    if (tid < 32) b1s[tid] = b1[tid];
    const float* xr = ws + o_AYt;
    for (int i = tid; i < 800; i += 128) {
        int c = i / 400, r = (i % 400) / 20, cc = i % 20;
        int gm = m0 - 2 + r, gb = b0 - 2 + cc;
        float v = 0.f;
        if (gm >= 0 && gm < M_N && gb >= 0 && gb < B_N)
            v = xr[(size_t)c * 524288 + (size_t)gm * B_N + gb];
        xw[c][r][cc] = v;
    }
    // A-fragments + bias (independent of LDS staging)
    int oc0w = wv * 32;
    const _Float16* Wa = (const _Float16*)(ws + o_w2t);
    half8 Af[2][9];
#pragma unroll
    for (int t = 0; t < 2; ++t)
#pragma unroll
        for (int kk = 0; kk < 9; ++kk)
            Af[t][kk] = *(const half8*)(Wa + ((size_t)(oc0w + t * 16 + col) * 9 + kk) * 32 + quad * 8);
    float bias[2][4];
#pragma unroll
    for (int t = 0; t < 2; ++t)
#pragma unroll
        for (int r = 0; r < 4; ++r)
            bias[t][r] = b2[oc0w + t * 16 + quad * 4 + r];
    __syncthreads();

    // ---- conv1 into zt (18x18 points, 3 rounds) ----
    for (int p = tid; p < 324; p += 128) {
        int ml = p / 18, bl = p % 18;
        int gm = m0 - 1 + ml, gb = b0 - 1 + bl;
        _Float16 zv[32];
        if (gm >= 0 && gm < M_N && gb >= 0 && gb < B_N) {
            for (int oc = 0; oc < 32; ++oc) {
                float acc = b1s[oc];
#pragma unroll
                for (int c = 0; c < 2; ++c)
#pragma unroll
                    for (int dm = 0; dm < 3; ++dm)
#pragma unroll
                        for (int db = 0; db < 3; ++db)
                            acc += xw[c][ml + dm][bl + db] * w1s[oc * 18 + c * 9 + dm * 3 + db];
                zv[oc] = (_Float16)fmaxf(acc, 0.f);
            }
        } else {
#pragma unroll
            for (int oc = 0; oc < 32; ++oc) zv[oc] = (_Float16)0.f;
        }
#pragma unroll
        for (int v = 0; v < 4; ++v) *(half8*)&zt[ml][bl][v * 8] = *(half8*)(zv + v * 8);
    }
    __syncthreads();

    // ---- conv2 MFMA; B-frag ring from LDS ----
    half8 Bf[3][3];
#pragma unroll
    for (int ph = 0; ph < 3; ++ph)
#pragma unroll
        for (int db = 0; db < 3; ++db)
            Bf[ph][db] = *(const half8*)&zt[ph][col + db][quad * 8];
    floatx4 facc[2];
    facc[0] = (floatx4){0.f, 0.f, 0.f, 0.f};
    facc[1] = (floatx4){0.f, 0.f, 0.f, 0.f};
#pragma unroll
    for (int mm = 0; mm < 16; ++mm) {
        floatx4 a0 = (floatx4){0.f, 0.f, 0.f, 0.f};
        floatx4 a1 = (floatx4){0.f, 0.f, 0.f, 0.f};
#pragma unroll
        for (int dm = 0; dm < 3; ++dm) {
            int ph = (mm + dm) % 3;
#pragma unroll
            for (int db = 0; db < 3; ++db) {
                MFMA16(Af[0][dm * 3 + db], Bf[ph][db], a0);
                MFMA16(Af[1][dm * 3 + db], Bf[ph][db], a1);
            }
        }
#pragma unroll
        for (int r = 0; r < 4; ++r) {
            facc[0][r] += fmaxf(a0[r] + bias[0][r], 0.f);
            facc[1][r] += fmaxf(a1[r] + bias[1][r], 0.f);
        }
        if (mm < 15) {
            int ph = mm % 3;
#pragma unroll
            for (int db = 0; db < 3; ++db)
                Bf[ph][db] = *(const half8*)&zt[mm + 3][col + db][quad * 8];
        }
    }
    float* fp = ws + o_fp + (size_t)g * 131072;
#pragma unroll
    for (int t = 0; t < 2; ++t)
#pragma unroll
        for (int r = 0; r < 4; ++r)
            fp[(size_t)(oc0w + t * 16 + quad * 4 + r) * B_N + b0 + col] = facc[t][r];
}

// ---------------- K3b: reduce 16 partials -> f = mean over M ----------------
__global__ void k_fred(float* __restrict__ ws) {
    size_t i = (size_t)blockIdx.x * 256 + threadIdx.x;
    float s = 0.f;
    for (int p = 0; p < 16; ++p) s += ws[o_fp + (size_t)p * 131072 + i];
    ws[o_f + i] = s * (1.f / 256.f);
}

// ---------------- K4: c,d,T 1-D convs; one l per block-row (grid 224) ----------------
__global__ void k_cdt(const float* __restrict__ hcw, const float* __restrict__ hcb,
                      const float* __restrict__ hdw, const float* __restrict__ hdb,
                      const float* __restrict__ hTw, const float* __restrict__ hTb,
                      float* __restrict__ ws, float* __restrict__ out) {
    int l = blockIdx.x >> 3;
    int b = (blockIdx.x & 7) * 256 + threadIdx.x;
    const float* f = ws + o_f;
    const float* w; float bi; int li, kind;
    if (l < 9)       { kind = 0; li = l;      w = hcw + (size_t)li * 192; bi = hcb[li]; }
    else if (l < 18) { kind = 1; li = l - 9;  w = hdw + (size_t)li * 192; bi = hdb[li]; }
    else             { kind = 2; li = l - 18; w = hTw + (size_t)li * 192; bi = hTb[li]; }
    __shared__ float wsm[192];
    for (int i = threadIdx.x; i < 192; i += 256) wsm[i] = w[i];
    __syncthreads();
    float acc = bi;
    bool okL = (b > 0), okR = (b < B_N - 1);
    for (int ic = 0; ic < 64; ++ic) {
        const float* fr = f + (size_t)ic * B_N + b;
        float fm1 = okL ? fr[-1] : 0.f;
        float f0  = fr[0];
        float fp1 = okR ? fr[1] : 0.f;
        acc += fm1 * wsm[ic * 3] + f0 * wsm[ic * 3 + 1] + fp1 * wsm[ic * 3 + 2];
    }
    float v = fmaxf(fabsf(acc), 1e-6f);
    if (kind != 1) v = fminf(v, 100.f);
    if (kind == 0)      { ws[o_c  + (size_t)b * 9  + li] = v; if (b == B_N - 1) out[524288 + li] = v; }
    else if (kind == 1) { ws[o_dd + (size_t)b * 9  + li] = v; if (b == B_N - 1) out[524297 + li] = v; }
    else                { ws[o_T  + (size_t)b * 10 + li] = v; if (b == B_N - 1) out[524306 + li] = v; }
}

// ---------------- K5: 10-layer iteration; dense AYt reads, LDS-transposed Ua stores ----
__global__ void __launch_bounds__(1024, 4)
k_iter(const float* __restrict__ a0p, const float* __restrict__ b0p, float* __restrict__ ws) {
    __shared__ __align__(16) _Float16 Ubf[2][8][64][8];   // 16 KB
    __shared__ __align__(16) float redv[16][52];
    __shared__ __align__(16) float UaT[16][260];
    __shared__ float redm[16];
    int tid = threadIdx.x;
    int lane = tid & 63, w = tid >> 6;
    int col = lane & 15, quad = lane >> 4;
    int b = blockIdx.x * 16 + col;
    const _Float16* Af = (const _Float16*)(ws + o_AA);
    float a0 = a0p[0], b0v = b0p[0];
    float atot = a0 + (float)NM;
    float yn = ws[o_yn + b];
    float eps = a0 / b0v;
    float Tv[10], cv[9], dvv[9];
#pragma unroll
    for (int i = 0; i < 10; ++i) Tv[i] = ws[o_T + (size_t)b * 10 + i];
#pragma unroll
    for (int i = 0; i < 9; ++i) cv[i] = ws[o_c + (size_t)b * 9 + i];
#pragma unroll
    for (int i = 0; i < 9; ++i) dvv[i] = ws[o_dd + (size_t)b * 9 + i];
    float lam0 = cv[0] * frcp(dvv[0]);
    half8 Ar8[8], Ai8[8];
#pragma unroll
    for (int ks = 0; ks < 8; ++ks) {
        const _Float16* ab = Af + ((size_t)(w * 8 + ks) * 64 + lane) * 8;
        Ar8[ks] = *(const half8*)(ab);
        Ai8[ks] = *(const half8*)(ab + 65536);
    }
    float Dv[4], ayr[4], ayi[4], lam[4], Ur[4], Ui[4], sg[4], wr_[4], wi_[4];
#pragma unroll
    for (int r = 0; r < 4; ++r) {
        int m = w * 16 + quad * 4 + r;
        Dv[r] = ws[o_D + m];
        ayr[r] = ws[o_AYt + (size_t)m * B_N + b];
        ayi[r] = ws[o_AYt + 524288 + (size_t)m * B_N + b];
        lam[r] = lam0;
        Ur[r] = 0.f; Ui[r] = 0.f; wr_[r] = 0.f; wi_[r] = 0.f;
    }
    int ksw = w >> 1;
    int quadD = (w & 1) * 2 + (quad >> 1);
    int laneD = quadD * 16 + col;
    int eb = (quad & 1) * 4;
    for (int k = 0; k < LNUM; ++k) {
        float Tk = Tv[k];
#pragma unroll
        for (int r = 0; r < 4; ++r) {
            float iv = eps * frcp(fmaf(eps, Tk, lam[r] + EPS_Sf));
            Ur[r] = iv * (Tk * Ur[r] - wr_[r] + ayr[r]);
            Ui[r] = iv * (Tk * Ui[r] - wi_[r] + ayi[r]);
        }
        if (k == LNUM - 1) break;
        {
            union { _Float16 h[4]; unsigned long long u; } c0, c2;
#pragma unroll
            for (int r = 0; r < 4; ++r) {
                c0.h[r] = (_Float16)Ur[r];
                c2.h[r] = (_Float16)Ui[r];
            }
            *(unsigned long long*)&Ubf[0][ksw][laneD][eb] = c0.u;
            *(unsigned long long*)&Ubf[1][ksw][laneD][eb] = c2.u;
        }
        __syncthreads();
        floatx4 wrp = (floatx4){0.f, 0.f, 0.f, 0.f};
        floatx4 wrn = (floatx4){0.f, 0.f, 0.f, 0.f};
        floatx4 wia1 = (floatx4){0.f, 0.f, 0.f, 0.f};
        floatx4 wia2 = (floatx4){0.f, 0.f, 0.f, 0.f};
#pragma unroll
        for (int ks = 0; ks < 8; ++ks) {
            half8 urh = *(const half8*)&Ubf[0][ks][lane][0];
            half8 uih = *(const half8*)&Ubf[1][ks][lane][0];
            MFMA16(Ar8[ks], urh, wrp);
            MFMA16(Ai8[ks], uih, wrn);
            MFMA16(Ar8[ks], uih, wia1);
            MFMA16(Ai8[ks], urh, wia2);
        }
        float p1 = 0.f, p2 = 0.f, p3 = 0.f;
#pragma unroll
        for (int r = 0; r < 4; ++r) {
            wr_[r] = wrp[r] - wrn[r];
            wi_[r] = wia1[r] + wia2[r];
            sg[r] = frcp(fmaf(eps, Dv[r], lam[r] + EPS_Sf));
            p1 += ayr[r] * Ur[r] + ayi[r] * Ui[r];
            p2 += Ur[r] * wr_[r] + Ui[r] * wi_[r];
            p3 += Dv[r] * sg[r];
        }
        p1 += __shfl_xor(p1, 16); p1 += __shfl_xor(p1, 32);
        p2 += __shfl_xor(p2, 16); p2 += __shfl_xor(p2, 32);
        p3 += __shfl_xor(p3, 16); p3 += __shfl_xor(p3, 32);
        if (lane < 16) {
            redv[col][w * 3]     = p1;
            redv[col][w * 3 + 1] = p2;
            redv[col][w * 3 + 2] = p3;
        }
        __syncthreads();
        float s[3] = {0.f, 0.f, 0.f};
#pragma unroll
        for (int j = 0; j < 12; ++j) {
            floatx4 v4 = *(const floatx4*)&redv[col][j * 4];
#pragma unroll
            for (int e = 0; e < 4; ++e) s[(j * 4 + e) % 3] += v4[e];
        }
        float eps1 = fmaxf(yn - 2.f * s[0] + s[1], 0.f);
        eps = atot * frcp(b0v + eps1 + s[2] + EPS_Sf);
        float ck1 = cv[k] + 1.f;
        float dk = dvv[k];
#pragma unroll
        for (int r = 0; r < 4; ++r)
            lam[r] = ck1 * frcp(dk + Ur[r] * Ur[r] + Ui[r] * Ui[r] + sg[r] + EPS_Sf);
    }
    float4 v;
    v.x = sqrtf(Ur[0] * Ur[0] + Ui[0] * Ui[0]);
    v.y = sqrtf(Ur[1] * Ur[1] + Ui[1] * Ui[1]);
    v.z = sqrtf(Ur[2] * Ur[2] + Ui[2] * Ui[2]);
    v.w = sqrtf(Ur[3] * Ur[3] + Ui[3] * Ui[3]);
    *(float4*)&UaT[col][w * 16 + quad * 4] = v;
    __syncthreads();
    float4 v2 = *(const float4*)&UaT[w][lane * 4];
    *(float4*)&ws[o_Ua + (size_t)(blockIdx.x * 16 + w) * M_N + lane * 4] = v2;
    float lm = fmaxf(fmaxf(v2.x, v2.y), fmaxf(v2.z, v2.w));
#pragma unroll
    for (int off = 32; off >= 1; off >>= 1) lm = fmaxf(lm, __shfl_xor(lm, off));
    if (lane == 0) redm[w] = lm;
    __syncthreads();
    if (tid == 0) {
        float mx = redm[0];
#pragma unroll
        for (int i = 1; i < 16; ++i) mx = fmaxf(mx, redm[i]);
        atomicMax((unsigned int*)(ws + o_gm), __float_as_uint(mx));
    }
}

// ---------------- K6: normalize ----------------
__global__ void k_norm(const float* __restrict__ ws, float* __restrict__ out) {
    size_t i = (size_t)blockIdx.x * 256 + threadIdx.x;
    float gm = __uint_as_float(*(const unsigned int*)(ws + o_gm));
    out[i] = ws[o_Ua + i] / (gm + 1e-8f);
}

extern "C" void kernel_launch(void* const* d_in, const int* in_sizes, int n_in,
                              void* d_out, int out_size, void* d_ws, size_t ws_size,
                              hipStream_t stream) {
    (void)in_sizes; (void)n_in; (void)out_size; (void)ws_size;
    const float* Yr  = (const float*)d_in[0];
    const float* Yi  = (const float*)d_in[1];
    const float* Ar  = (const float*)d_in[2];
    const float* Ai  = (const float*)d_in[3];
    const float* w1  = (const float*)d_in[4];
    const float* b1  = (const float*)d_in[5];
    const float* w2  = (const float*)d_in[6];
    const float* b2  = (const float*)d_in[7];
    const float* hcw = (const float*)d_in[8];
    const float* hcb = (const float*)d_in[9];
    const float* hdw = (const float*)d_in[10];
    const float* hdb = (const float*)d_in[11];
    const float* hTw = (const float*)d_in[12];
    const float* hTb = (const float*)d_in[13];
    const float* a0  = (const float*)d_in[14];
    const float* b0  = (const float*)d_in[15];
    float* ws = (float*)d_ws;
    float* out = (float*)d_out;

    k_pre   <<<584, 256, 0, stream>>>(Ar, Ai, Yr, Yi, w2, ws);
    k_conv12<<<2048, 128, 0, stream>>>(w1, b1, b2, ws);
    k_fred  <<<512, 256, 0, stream>>>(ws);
    k_cdt   <<<224, 256, 0, stream>>>(hcw, hcb, hdw, hdb, hTw, hTb, ws, out);
    k_iter  <<<128, 1024, 0, stream>>>(a0, b0, ws);
    k_norm  <<<2048, 256, 0, stream>>>(ws, out);
}

// Round 13
// 224.547 us; speedup vs baseline: 1.4152x; 1.4152x over previous
//
#include <hip/hip_runtime.h>
#include <math.h>

#define B_N   2048
#define NM    128
#define M_N   256
#define LNUM  10
#define EPS_Sf 1e-6f

typedef _Float16 half8 __attribute__((ext_vector_type(8)));
typedef float floatx4 __attribute__((ext_vector_type(4)));

__device__ __forceinline__ float frcp(float x) { return __builtin_amdgcn_rcpf(x); }

// ---------------- workspace layout (float offsets) ----------------
static constexpr size_t o_AA  = 0;                       // 2 f16 planes, frag order
static constexpr size_t o_D   = o_AA  + 131072;          // 256
static constexpr size_t o_yn  = o_D   + 256;             // 2048
static constexpr size_t o_AY  = o_yn  + 2048;            // float2[B*M]
static constexpr size_t o_AYt = o_AY  + 1048576;         // [2][256][2048]
static constexpr size_t o_w2t = o_AYt + 1048576;         // Wa f16 [oc64][kk9][ic32]
static constexpr size_t o_z1  = o_w2t + 18432;           // z1t f16 [258][2050][32]
static constexpr size_t o_fp  = o_z1  + 16777216;        // [16][64][2048] fp32 partials
static constexpr size_t o_f   = o_fp  + 2097152;         // [64][2048]
static constexpr size_t o_c   = o_f   + 131072;          // [2048][9]
static constexpr size_t o_dd  = o_c   + 18432;           // [2048][9]
static constexpr size_t o_T   = o_dd  + 18432;           // [2048][10]
static constexpr size_t o_Ua  = o_T   + 20480;           // 524288
static constexpr size_t o_gm  = o_Ua  + 524288;          // 1

#define Z1T_RS (2050 * 32)

// ---------------- K_pre: fused {gm=0, AA->f16 frag, w2 transpose, AY} ----------------
// blocks [0,256) : k_aa rows ; [256,328) : w2t ; [328,584) : k_ay groups
__global__ void k_pre(const float* __restrict__ Ar, const float* __restrict__ Ai,
                      const float* __restrict__ Yr, const float* __restrict__ Yi,
                      const float* __restrict__ w2, float* __restrict__ ws) {
    __shared__ float sb[2048];
    int blk = blockIdx.x;
    int tid = threadIdx.x;
    if (blk < 256) {
        float* cr = sb; float* ci = sb + NM;
        int i = blk, j = tid;
        if (j < NM) { cr[j] = Ar[j * M_N + i]; ci[j] = Ai[j * M_N + i]; }
        __syncthreads();
        float sr = 0.f, si = 0.f;
        for (int n = 0; n < NM; ++n) {
            float ar = Ar[n * M_N + j], ai = Ai[n * M_N + j];
            sr += cr[n] * ar + ci[n] * ai;
            si += cr[n] * ai - ci[n] * ar;
        }
        _Float16* A16 = (_Float16*)(ws + o_AA);
        size_t off = ((size_t)((i >> 4) * 8 + (j >> 5)) * 64
                      + (size_t)(((j >> 3) & 3) * 16 + (i & 15))) * 8 + (j & 7);
        A16[off]         = (_Float16)sr;
        A16[65536 + off] = (_Float16)si;
        if (j == i) ws[o_D + i] = sr;
        if (i == 0 && j == 0) *(unsigned int*)(ws + o_gm) = 0u;
    } else if (blk < 328) {
        int i = (blk - 256) * 256 + tid;
        if (i < 64 * 32 * 9) {
            int oc = i / 288, r = i % 288;
            int ic = r / 9, kk = r % 9;
            _Float16* Wa = (_Float16*)(ws + o_w2t);
            Wa[((size_t)oc * 9 + kk) * 32 + ic] = (_Float16)w2[i];
        }
    } else {
        float2* Ys = (float2*)sb;
        int bb0 = (blk - 328) * 8;
        for (int i = tid; i < 8 * NM; i += 256) {
            int g = i >> 7, n = i & 127;
            Ys[g * NM + n] = make_float2(Yr[(size_t)(bb0 + g) * NM + n],
                                         Yi[(size_t)(bb0 + g) * NM + n]);
        }
        __syncthreads();
        if (tid < 8) {
            float s = 0.f;
            for (int n = 0; n < NM; ++n) { float2 y = Ys[tid * NM + n]; s += y.x * y.x + y.y * y.y; }
            ws[o_yn + bb0 + tid] = s;
        }
        int m = tid;
        float accr[8], acci[8];
#pragma unroll
        for (int g = 0; g < 8; ++g) { accr[g] = 0.f; acci[g] = 0.f; }
        for (int n = 0; n < NM; ++n) {
            float ar = Ar[n * M_N + m], ai = Ai[n * M_N + m];
#pragma unroll
            for (int g = 0; g < 8; ++g) {
                float2 y = Ys[g * NM + n];
                accr[g] += ar * y.x + ai * y.y;
                acci[g] += ar * y.y - ai * y.x;
            }
        }
        float2* AY = (float2*)(ws + o_AY);
#pragma unroll
        for (int g = 0; g < 8; ++g) {
            AY[(size_t)(bb0 + g) * M_N + m] = make_float2(accr[g], acci[g]);
            ws[o_AYt + (size_t)m * B_N + (bb0 + g)] = accr[g];
            ws[o_AYt + 524288 + (size_t)m * B_N + (bb0 + g)] = acci[g];
        }
    }
}

// ---------------- K2: conv1 (2->32) + ReLU -> z1t f16 [m+1][b+1][ic], zero halo ----------
// lane = b: contiguous 64B/lane stores. (R8's 4-col variant thrashed HBM; R12's LDS-fused
// variant turned every FMA into an LDS read — keep this register-window form.)
__global__ void k_conv1(const float* __restrict__ w1, const float* __restrict__ b1,
                        float* __restrict__ ws) {
    __shared__ float w1s[576], b1s[32];
    int tid = threadIdx.x;
    for (int i = tid; i < 576; i += 256) w1s[i] = w1[i];
    if (tid < 32) b1s[tid] = b1[tid];
    __syncthreads();
    int gidx = blockIdx.x * 256 + tid;
    int b = gidx & (B_N - 1), m = gidx >> 11;
    const float* xr = ws + o_AYt;
    float x[2][3][3];
#pragma unroll
    for (int c = 0; c < 2; ++c)
#pragma unroll
        for (int dm = 0; dm < 3; ++dm) {
            int mm = m + dm - 1;
#pragma unroll
            for (int db = 0; db < 3; ++db) {
                int bb = b + db - 1;
                x[c][dm][db] = (mm >= 0 && mm < M_N && bb >= 0 && bb < B_N)
                                 ? xr[(size_t)c * 524288 + (size_t)mm * B_N + bb] : 0.f;
            }
        }
    _Float16* z1t = (_Float16*)(ws + o_z1);
    _Float16 zv[32];
    for (int oc = 0; oc < 32; ++oc) {
        float acc = b1s[oc];
#pragma unroll
        for (int c = 0; c < 2; ++c)
#pragma unroll
            for (int dm = 0; dm < 3; ++dm)
#pragma unroll
                for (int db = 0; db < 3; ++db)
                    acc += x[c][dm][db] * w1s[oc * 18 + c * 9 + dm * 3 + db];
        zv[oc] = (_Float16)fmaxf(acc, 0.f);
    }
    _Float16* dst = z1t + (size_t)(m + 1) * Z1T_RS + (size_t)(b + 1) * 32;
#pragma unroll
    for (int v = 0; v < 4; ++v) *(half8*)(dst + v * 8) = *(half8*)(zv + v * 8);
    half8 z8 = (half8)((_Float16)0.f);
    if (m == 0) {
        _Float16* d2 = z1t + (size_t)(b + 1) * 32;
#pragma unroll
        for (int v = 0; v < 4; ++v) *(half8*)(d2 + v * 8) = z8;
        if (b == 0) { _Float16* d3 = z1t;
#pragma unroll
            for (int v = 0; v < 4; ++v) *(half8*)(d3 + v * 8) = z8; }
        if (b == B_N - 1) { _Float16* d3 = z1t + (size_t)2049 * 32;
#pragma unroll
            for (int v = 0; v < 4; ++v) *(half8*)(d3 + v * 8) = z8; }
    }
    if (m == M_N - 1) {
        _Float16* d2 = z1t + (size_t)257 * Z1T_RS + (size_t)(b + 1) * 32;
#pragma unroll
        for (int v = 0; v < 4; ++v) *(half8*)(d2 + v * 8) = z8;
        if (b == 0) { _Float16* d3 = z1t + (size_t)257 * Z1T_RS;
#pragma unroll
            for (int v = 0; v < 4; ++v) *(half8*)(d3 + v * 8) = z8; }
        if (b == B_N - 1) { _Float16* d3 = z1t + (size_t)257 * Z1T_RS + (size_t)2049 * 32;
#pragma unroll
            for (int v = 0; v < 4; ++v) *(half8*)(d3 + v * 8) = z8; }
    }
    if (b == 0) {
        _Float16* d2 = z1t + (size_t)(m + 1) * Z1T_RS;
#pragma unroll
        for (int v = 0; v < 4; ++v) *(half8*)(d2 + v * 8) = z8;
    }
    if (b == B_N - 1) {
        _Float16* d2 = z1t + (size_t)(m + 1) * Z1T_RS + (size_t)2049 * 32;
#pragma unroll
        for (int v = 0; v < 4; ++v) *(half8*)(d2 + v * 8) = z8;
    }
}

// ---------------- K3: conv2 implicit-GEMM MFMA ----------------
#define MFMA16(A,Bv,C) C = __builtin_amdgcn_mfma_f32_16x16x32_f16(A, Bv, C, 0, 0, 0)
__global__ void __launch_bounds__(128)
k_conv2m(const float* __restrict__ b2, float* __restrict__ ws) {
    int tid = threadIdx.x;
    int lane = tid & 63, wv = tid >> 6;
    int col = lane & 15, quad = lane >> 4;
    int bt = blockIdx.x & 127, g = blockIdx.x >> 7;
    int b0 = bt * 16, m0 = g * 16;
    int oc0w = wv * 32;
    const _Float16* z1t = (const _Float16*)(ws + o_z1);
    const _Float16* Wa  = (const _Float16*)(ws + o_w2t);

    half8 Af[2][9];
#pragma unroll
    for (int t = 0; t < 2; ++t)
#pragma unroll
        for (int kk = 0; kk < 9; ++kk)
            Af[t][kk] = *(const half8*)(Wa + ((size_t)(oc0w + t * 16 + col) * 9 + kk) * 32 + quad * 8);
    float bias[2][4];
#pragma unroll
    for (int t = 0; t < 2; ++t)
#pragma unroll
        for (int r = 0; r < 4; ++r)
            bias[t][r] = b2[oc0w + t * 16 + quad * 4 + r];

    const _Float16* zb = z1t + (size_t)(b0 + col) * 32 + quad * 8;
    half8 Bf[3][3];
#pragma unroll
    for (int ph = 0; ph < 3; ++ph)
#pragma unroll
        for (int db = 0; db < 3; ++db)
            Bf[ph][db] = *(const half8*)(zb + (size_t)(m0 + ph) * Z1T_RS + (size_t)db * 32);

    floatx4 facc[2];
    facc[0] = (floatx4){0.f, 0.f, 0.f, 0.f};
    facc[1] = (floatx4){0.f, 0.f, 0.f, 0.f};

#pragma unroll
    for (int mm = 0; mm < 16; ++mm) {
        floatx4 a0 = (floatx4){0.f, 0.f, 0.f, 0.f};
        floatx4 a1 = (floatx4){0.f, 0.f, 0.f, 0.f};
#pragma unroll
        for (int dm = 0; dm < 3; ++dm) {
            int ph = (mm + dm) % 3;
#pragma unroll
            for (int db = 0; db < 3; ++db) {
                MFMA16(Af[0][dm * 3 + db], Bf[ph][db], a0);
                MFMA16(Af[1][dm * 3 + db], Bf[ph][db], a1);
            }
        }
#pragma unroll
        for (int r = 0; r < 4; ++r) {
            facc[0][r] += fmaxf(a0[r] + bias[0][r], 0.f);
            facc[1][r] += fmaxf(a1[r] + bias[1][r], 0.f);
        }
        if (mm < 15) {
            int ph = mm % 3;
#pragma unroll
            for (int db = 0; db < 3; ++db)
                Bf[ph][db] = *(const half8*)(zb + (size_t)(m0 + mm + 3) * Z1T_RS + (size_t)db * 32);
        }
    }
    float* fp = ws + o_fp + (size_t)g * 131072;
#pragma unroll
    for (int t = 0; t < 2; ++t)
#pragma unroll
        for (int r = 0; r < 4; ++r)
            fp[(size_t)(oc0w + t * 16 + quad * 4 + r) * B_N + b0 + col] = facc[t][r];
}

// ---------------- K3b: reduce 16 partials -> f = mean over M ----------------
__global__ void k_fred(float* __restrict__ ws) {
    size_t i = (size_t)blockIdx.x * 256 + threadIdx.x;
    float s = 0.f;
    for (int p = 0; p < 16; ++p) s += ws[o_fp + (size_t)p * 131072 + i];
    ws[o_f + i] = s * (1.f / 256.f);
}

// ---------------- K4: c,d,T 1-D convs; one l per block-row (grid 224) ----------------
__global__ void k_cdt(const float* __restrict__ hcw, const float* __restrict__ hcb,
                      const float* __restrict__ hdw, const float* __restrict__ hdb,
                      const float* __restrict__ hTw, const float* __restrict__ hTb,
                      float* __restrict__ ws, float* __restrict__ out) {
    int l = blockIdx.x >> 3;
    int b = (blockIdx.x & 7) * 256 + threadIdx.x;
    const float* f = ws + o_f;
    const float* w; float bi; int li, kind;
    if (l < 9)       { kind = 0; li = l;      w = hcw + (size_t)li * 192; bi = hcb[li]; }
    else if (l < 18) { kind = 1; li = l - 9;  w = hdw + (size_t)li * 192; bi = hdb[li]; }
    else             { kind = 2; li = l - 18; w = hTw + (size_t)li * 192; bi = hTb[li]; }
    __shared__ float wsm[192];
    for (int i = threadIdx.x; i < 192; i += 256) wsm[i] = w[i];
    __syncthreads();
    float acc = bi;
    bool okL = (b > 0), okR = (b < B_N - 1);
    for (int ic = 0; ic < 64; ++ic) {
        const float* fr = f + (size_t)ic * B_N + b;
        float fm1 = okL ? fr[-1] : 0.f;
        float f0  = fr[0];
        float fp1 = okR ? fr[1] : 0.f;
        acc += fm1 * wsm[ic * 3] + f0 * wsm[ic * 3 + 1] + fp1 * wsm[ic * 3 + 2];
    }
    float v = fmaxf(fabsf(acc), 1e-6f);
    if (kind != 1) v = fminf(v, 100.f);
    if (kind == 0)      { ws[o_c  + (size_t)b * 9  + li] = v; if (b == B_N - 1) out[524288 + li] = v; }
    else if (kind == 1) { ws[o_dd + (size_t)b * 9  + li] = v; if (b == B_N - 1) out[524297 + li] = v; }
    else                { ws[o_T  + (size_t)b * 10 + li] = v; if (b == B_N - 1) out[524306 + li] = v; }
}

// ---------------- K5: 10-layer iteration; zero global traffic inside loop ----------------
__global__ void __launch_bounds__(1024, 4)
k_iter(const float* __restrict__ a0p, const float* __restrict__ b0p, float* __restrict__ ws) {
    __shared__ __align__(16) _Float16 Ubf[2][8][64][8];   // 16 KB
    __shared__ __align__(16) float redv[16][52];
    __shared__ float redm[16];
    int tid = threadIdx.x;
    int lane = tid & 63, w = tid >> 6;
    int col = lane & 15, quad = lane >> 4;
    int b = blockIdx.x * 16 + col;
    const float2* AY = (const float2*)(ws + o_AY);
    const _Float16* Af = (const _Float16*)(ws + o_AA);
    float a0 = a0p[0], b0v = b0p[0];
    float atot = a0 + (float)NM;
    float yn = ws[o_yn + b];
    float eps = a0 / b0v;
    float Tv[10], cv[9], dvv[9];
#pragma unroll
    for (int i = 0; i < 10; ++i) Tv[i] = ws[o_T + (size_t)b * 10 + i];
#pragma unroll
    for (int i = 0; i < 9; ++i) cv[i] = ws[o_c + (size_t)b * 9 + i];
#pragma unroll
    for (int i = 0; i < 9; ++i) dvv[i] = ws[o_dd + (size_t)b * 9 + i];
    float lam0 = cv[0] * frcp(dvv[0]);
    half8 Ar8[8], Ai8[8];
#pragma unroll
    for (int ks = 0; ks < 8; ++ks) {
        const _Float16* ab = Af + ((size_t)(w * 8 + ks) * 64 + lane) * 8;
        Ar8[ks] = *(const half8*)(ab);
        Ai8[ks] = *(const half8*)(ab + 65536);
    }
    float Dv[4], ayr[4], ayi[4], lam[4], Ur[4], Ui[4], sg[4], wr_[4], wi_[4];
#pragma unroll
    for (int r = 0; r < 4; ++r) {
        int m = w * 16 + quad * 4 + r;
        Dv[r] = ws[o_D + m];
        float2 a = AY[(size_t)b * M_N + m];
        ayr[r] = a.x; ayi[r] = a.y;
        lam[r] = lam0;
        Ur[r] = 0.f; Ui[r] = 0.f; wr_[r] = 0.f; wi_[r] = 0.f;
    }
    int ksw = w >> 1;
    int quadD = (w & 1) * 2 + (quad >> 1);
    int laneD = quadD * 16 + col;
    int eb = (quad & 1) * 4;
    for (int k = 0; k < LNUM; ++k) {
        float Tk = Tv[k];
#pragma unroll
        for (int r = 0; r < 4; ++r) {
            float iv = eps * frcp(fmaf(eps, Tk, lam[r] + EPS_Sf));
            Ur[r] = iv * (Tk * Ur[r] - wr_[r] + ayr[r]);
            Ui[r] = iv * (Tk * Ui[r] - wi_[r] + ayi[r]);
        }
        if (k == LNUM - 1) break;
        {
            union { _Float16 h[4]; unsigned long long u; } c0, c2;
#pragma unroll
            for (int r = 0; r < 4; ++r) {
                c0.h[r] = (_Float16)Ur[r];
                c2.h[r] = (_Float16)Ui[r];
            }
            *(unsigned long long*)&Ubf[0][ksw][laneD][eb] = c0.u;
            *(unsigned long long*)&Ubf[1][ksw][laneD][eb] = c2.u;
        }
        __syncthreads();
        floatx4 wrp = (floatx4){0.f, 0.f, 0.f, 0.f};
        floatx4 wrn = (floatx4){0.f, 0.f, 0.f, 0.f};
        floatx4 wia1 = (floatx4){0.f, 0.f, 0.f, 0.f};
        floatx4 wia2 = (floatx4){0.f, 0.f, 0.f, 0.f};
#pragma unroll
        for (int ks = 0; ks < 8; ++ks) {
            half8 urh = *(const half8*)&Ubf[0][ks][lane][0];
            half8 uih = *(const half8*)&Ubf[1][ks][lane][0];
            MFMA16(Ar8[ks], urh, wrp);
            MFMA16(Ai8[ks], uih, wrn);
            MFMA16(Ar8[ks], uih, wia1);
            MFMA16(Ai8[ks], urh, wia2);
        }
        float p1 = 0.f, p2 = 0.f, p3 = 0.f;
#pragma unroll
        for (int r = 0; r < 4; ++r) {
            wr_[r] = wrp[r] - wrn[r];
            wi_[r] = wia1[r] + wia2[r];
            sg[r] = frcp(fmaf(eps, Dv[r], lam[r] + EPS_Sf));
            p1 += ayr[r] * Ur[r] + ayi[r] * Ui[r];
            p2 += Ur[r] * wr_[r] + Ui[r] * wi_[r];
            p3 += Dv[r] * sg[r];
        }
        p1 += __shfl_xor(p1, 16); p1 += __shfl_xor(p1, 32);
        p2 += __shfl_xor(p2, 16); p2 += __shfl_xor(p2, 32);
        p3 += __shfl_xor(p3, 16); p3 += __shfl_xor(p3, 32);
        if (lane < 16) {
            redv[col][w * 3]     = p1;
            redv[col][w * 3 + 1] = p2;
            redv[col][w * 3 + 2] = p3;
        }
        __syncthreads();
        float s[3] = {0.f, 0.f, 0.f};
#pragma unroll
        for (int j = 0; j < 12; ++j) {
            floatx4 v4 = *(const floatx4*)&redv[col][j * 4];
#pragma unroll
            for (int e = 0; e < 4; ++e) s[(j * 4 + e) % 3] += v4[e];
        }
        float eps1 = fmaxf(yn - 2.f * s[0] + s[1], 0.f);
        eps = atot * frcp(b0v + eps1 + s[2] + EPS_Sf);
        float ck1 = cv[k] + 1.f;
        float dk = dvv[k];
#pragma unroll
        for (int r = 0; r < 4; ++r)
            lam[r] = ck1 * frcp(dk + Ur[r] * Ur[r] + Ui[r] * Ui[r] + sg[r] + EPS_Sf);
    }
    float4 v;
    v.x = sqrtf(Ur[0] * Ur[0] + Ui[0] * Ui[0]);
    v.y = sqrtf(Ur[1] * Ur[1] + Ui[1] * Ui[1]);
    v.z = sqrtf(Ur[2] * Ur[2] + Ui[2] * Ui[2]);
    v.w = sqrtf(Ur[3] * Ur[3] + Ui[3] * Ui[3]);
    *(float4*)&ws[o_Ua + (size_t)b * M_N + w * 16 + quad * 4] = v;
    float lm = fmaxf(fmaxf(v.x, v.y), fmaxf(v.z, v.w));
#pragma unroll
    for (int off = 32; off >= 1; off >>= 1) lm = fmaxf(lm, __shfl_xor(lm, off));
    if (lane == 0) redm[w] = lm;
    __syncthreads();
    if (tid == 0) {
        float mx = redm[0];
#pragma unroll
        for (int i = 1; i < 16; ++i) mx = fmaxf(mx, redm[i]);
        atomicMax((unsigned int*)(ws + o_gm), __float_as_uint(mx));
    }
}

// ---------------- K6: normalize ----------------
__global__ void k_norm(const float* __restrict__ ws, float* __restrict__ out) {
    size_t i = (size_t)blockIdx.x * 256 + threadIdx.x;
    float gm = __uint_as_float(*(const unsigned int*)(ws + o_gm));
    out[i] = ws[o_Ua + i] / (gm + 1e-8f);
}

extern "C" void kernel_launch(void* const* d_in, const int* in_sizes, int n_in,
                              void* d_out, int out_size, void* d_ws, size_t ws_size,
                              hipStream_t stream) {
    (void)in_sizes; (void)n_in; (void)out_size; (void)ws_size;
    const float* Yr  = (const float*)d_in[0];
    const float* Yi  = (const float*)d_in[1];
    const float* Ar  = (const float*)d_in[2];
    const float* Ai  = (const float*)d_in[3];
    const float* w1  = (const float*)d_in[4];
    const float* b1  = (const float*)d_in[5];
    const float* w2  = (const float*)d_in[6];
    const float* b2  = (const float*)d_in[7];
    const float* hcw = (const float*)d_in[8];
    const float* hcb = (const float*)d_in[9];
    const float* hdw = (const float*)d_in[10];
    const float* hdb = (const float*)d_in[11];
    const float* hTw = (const float*)d_in[12];
    const float* hTb = (const float*)d_in[13];
    const float* a0  = (const float*)d_in[14];
    const float* b0  = (const float*)d_in[15];
    float* ws = (float*)d_ws;
    float* out = (float*)d_out;

    k_pre   <<<584, 256, 0, stream>>>(Ar, Ai, Yr, Yi, w2, ws);
    k_conv1 <<<2048, 256, 0, stream>>>(w1, b1, ws);
    k_conv2m<<<2048, 128, 0, stream>>>(b2, ws);
    k_fred  <<<512, 256, 0, stream>>>(ws);
    k_cdt   <<<224, 256, 0, stream>>>(hcw, hcb, hdw, hdb, hTw, hTb, ws, out);
    k_iter  <<<128, 1024, 0, stream>>>(a0, b0, ws);
    k_norm  <<<2048, 256, 0, stream>>>(ws, out);
}